// Round 2
// baseline (872.410 us; speedup 1.0000x reference)
//
#include <hip/hip_runtime.h>
#include <stdint.h>

// Problem constants
#define NB 32
#define NQd 1024
#define NKd 2048
#define DDd 256

typedef __attribute__((ext_vector_type(4))) float f32x4;
typedef __attribute__((ext_vector_type(8))) short s16x8;

__device__ __forceinline__ unsigned short f2bf(float f) {
  unsigned int u = __builtin_bit_cast(unsigned int, f);
  u += 0x7fffu + ((u >> 16) & 1u);   // RNE round to bf16
  return (unsigned short)(u >> 16);
}

// ---------------------------------------------------------------------------
// Projection GEMM: C[m][n] = sum_k P[m*256+k] * Q[n*256+k] (+ bias), bf16 out.
// MODE 0: out[m*256+n], bias[n]   (q and k projections, row-major)
// MODE 1: out[(n/2048)*524288 + m*2048 + (n%2048)], bias[m]  (vT, transposed)
// Tiles: BM=128, BN=128, BK=64. 512 threads = 8 waves (2m x 4n).
// ---------------------------------------------------------------------------
template <int MODE>
__global__ __launch_bounds__(512) void proj_kernel(
    const float* __restrict__ P, const float* __restrict__ Q,
    const float* __restrict__ bias, unsigned short* __restrict__ out) {
  __shared__ __align__(16) char lds[32768];  // P tile 16KB + Q tile 16KB
  char* Pl = lds;
  char* Ql = lds + 16384;

  const int tid = threadIdx.x;
  const int m0 = blockIdx.x * 128, n0 = blockIdx.y * 128;
  const int lane = tid & 63, w = tid >> 6;
  const int lr = lane & 15, lg = lane >> 4;
  const int wm = w >> 2, wn = w & 3;  // wave grid 2 x 4

  f32x4 acc[4][2];
#pragma unroll
  for (int a = 0; a < 4; a++)
#pragma unroll
    for (int b2 = 0; b2 < 2; b2++) acc[a][b2] = (f32x4){0.f, 0.f, 0.f, 0.f};

  for (int k0 = 0; k0 < 256; k0 += 64) {
    __syncthreads();
    // stage both tiles: 128 rows x 64 k each -> 1024 16B-chunks each
#pragma unroll
    for (int j = 0; j < 2; j++) {
      int c = tid + j * 512;
      int row = c >> 3, cc = c & 7;
      int dst = row * 128 + ((cc * 16) ^ ((row & 7) << 4));
      {
        const float* src = P + (size_t)(m0 + row) * 256 + k0 + cc * 8;
        f32x4 x = *(const f32x4*)src;
        f32x4 y = *(const f32x4*)(src + 4);
        s16x8 pk;
        pk[0] = (short)f2bf(x[0]); pk[1] = (short)f2bf(x[1]);
        pk[2] = (short)f2bf(x[2]); pk[3] = (short)f2bf(x[3]);
        pk[4] = (short)f2bf(y[0]); pk[5] = (short)f2bf(y[1]);
        pk[6] = (short)f2bf(y[2]); pk[7] = (short)f2bf(y[3]);
        *(s16x8*)(Pl + dst) = pk;
      }
      {
        const float* src = Q + (size_t)(n0 + row) * 256 + k0 + cc * 8;
        f32x4 x = *(const f32x4*)src;
        f32x4 y = *(const f32x4*)(src + 4);
        s16x8 pk;
        pk[0] = (short)f2bf(x[0]); pk[1] = (short)f2bf(x[1]);
        pk[2] = (short)f2bf(x[2]); pk[3] = (short)f2bf(x[3]);
        pk[4] = (short)f2bf(y[0]); pk[5] = (short)f2bf(y[1]);
        pk[6] = (short)f2bf(y[2]); pk[7] = (short)f2bf(y[3]);
        *(s16x8*)(Ql + dst) = pk;
      }
    }
    __syncthreads();
#pragma unroll
    for (int ks = 0; ks < 2; ks++) {
      s16x8 af[4], bf[2];
      int kbyte = ks * 64 + lg * 16;
#pragma unroll
      for (int fm = 0; fm < 4; fm++) {
        int row = wm * 64 + fm * 16 + lr;
        af[fm] = *(const s16x8*)(Pl + row * 128 + (kbyte ^ ((row & 7) << 4)));
      }
#pragma unroll
      for (int fn = 0; fn < 2; fn++) {
        int row = wn * 32 + fn * 16 + lr;
        bf[fn] = *(const s16x8*)(Ql + row * 128 + (kbyte ^ ((row & 7) << 4)));
      }
#pragma unroll
      for (int fm = 0; fm < 4; fm++)
#pragma unroll
        for (int fn = 0; fn < 2; fn++)
          acc[fm][fn] = __builtin_amdgcn_mfma_f32_16x16x32_bf16(
              af[fm], bf[fn], acc[fm][fn], 0, 0, 0);
    }
  }

  if (MODE == 0) {
    float bv[2];
#pragma unroll
    for (int fn = 0; fn < 2; fn++) bv[fn] = bias[n0 + wn * 32 + fn * 16 + lr];
#pragma unroll
    for (int fm = 0; fm < 4; fm++)
#pragma unroll
      for (int i = 0; i < 4; i++) {
        int m = m0 + wm * 64 + fm * 16 + lg * 4 + i;
#pragma unroll
        for (int fn = 0; fn < 2; fn++) {
          int n = n0 + wn * 32 + fn * 16 + lr;
          out[(size_t)m * 256 + n] = f2bf(acc[fm][fn][i] + bv[fn]);
        }
      }
  } else {
#pragma unroll
    for (int fm = 0; fm < 4; fm++)
#pragma unroll
      for (int i = 0; i < 4; i++) {
        int m = m0 + wm * 64 + fm * 16 + lg * 4 + i;  // d index
        float bm = bias[m];
#pragma unroll
        for (int fn = 0; fn < 2; fn++) {
          int n = n0 + wn * 32 + fn * 16 + lr;  // global key row
          int bb = n >> 11, nn = n & 2047;
          out[(size_t)bb * 524288 + (size_t)m * 2048 + nn] =
              f2bf(acc[fm][fn][i] + bm);
        }
      }
  }
}

// ---------------------------------------------------------------------------
// Attention: grid 512 = B(32) x q-tiles(16). Block: 64 q-rows, 512 thr/8 waves.
// Per k-tile (64 keys): stage K[64][256] + vT[256][64] (bf16, XOR-swizzled),
// S = QK^T/16 + bias, mask, s=exp (no max-sub; qmask==0 row -> s=1 uniform),
// write unnormalized s to weights, s->bf16->LDS, O += S*V. End: rowsums, O/sum.
// LDS 64KB exactly: Kl[0,32K) (S region + rowsums alias its head), Vl[32K,64K).
// ---------------------------------------------------------------------------
__global__ __launch_bounds__(512) void attn_kernel(
    const unsigned short* __restrict__ qb, const unsigned short* __restrict__ kb,
    const unsigned short* __restrict__ vT, const int* __restrict__ qmask,
    const int* __restrict__ kmask, const float* __restrict__ bias,
    float* __restrict__ out, float* __restrict__ weights,
    float* __restrict__ rowsum_ws) {
  __shared__ __align__(16) char lds[65536];
  char* Kl = lds;           // 32KB, rows 64 x 512B, swizzled
  char* Vl = lds + 32768;   // 32KB, rows 256 x 128B, swizzled
  char* Sl = lds;           // 8KB, rows 64 x 128B (aliases Kl; barrier-separated)
  float* rowsum_lds = (float*)lds;  // used only after the k-loop

  int bid = blockIdx.x;
  int swz = (bid & 7) * 64 + (bid >> 3);  // XCD-aware swizzle (512 % 8 == 0)
  int b = swz >> 4, qt = swz & 15;
  int q0 = qt * 64;
  const int tid = threadIdx.x, lane = tid & 63, w = tid >> 6;
  const int lr = lane & 15, lg = lane >> 4;
  const int wm = w >> 2, wn = w & 3;  // 2(m) x 4(n)

  // Hoist Q fragments: rows q0+wm*32+fm*16+lr, k-chunks ks*32+lg*8 (64 VGPRs)
  s16x8 qf[2][8];
  {
    const unsigned short* qbase =
        qb + (size_t)(b * 1024 + q0 + wm * 32 + lr) * 256 + lg * 8;
#pragma unroll
    for (int fm = 0; fm < 2; fm++)
#pragma unroll
      for (int ks = 0; ks < 8; ks++)
        qf[fm][ks] = *(const s16x8*)(qbase + fm * 16 * 256 + ks * 32);
  }
  // qmask bits for this lane's S rows
  unsigned qmbits = 0;
#pragma unroll
  for (int fm = 0; fm < 2; fm++)
#pragma unroll
    for (int i = 0; i < 4; i++) {
      int qm = qmask[b * 1024 + q0 + wm * 32 + fm * 16 + lg * 4 + i];
      qmbits |= (qm ? 1u : 0u) << (fm * 4 + i);
    }

  f32x4 acc_o[2][4];
#pragma unroll
  for (int a = 0; a < 2; a++)
#pragma unroll
    for (int c = 0; c < 4; c++) acc_o[a][c] = (f32x4){0.f, 0.f, 0.f, 0.f};
  float rs[2][4];
#pragma unroll
  for (int a = 0; a < 2; a++)
#pragma unroll
    for (int i = 0; i < 4; i++) rs[a][i] = 0.f;

  const size_t kb_base = (size_t)b * 2048 * 256;
  const size_t vT_base = (size_t)b * 256 * 2048;

  for (int kt = 0; kt < 32; kt++) {
    __syncthreads();  // previous PV done before overwriting K/V/S regions
    // ---- stage K tile (2048 chunks) and vT tile (2048 chunks), swizzled ----
#pragma unroll
    for (int j = 0; j < 4; j++) {
      int c = tid + j * 512;
      {
        int row = c >> 5, cb = (c & 31) * 16;
        s16x8 kv = *(const s16x8*)(kb + kb_base +
                                   (size_t)(kt * 64 + row) * 256 + (cb >> 1));
        *(s16x8*)(Kl + row * 512 + (cb ^ ((row & 7) << 4))) = kv;
      }
      {
        int row = c >> 3, cb = (c & 7) * 16;
        s16x8 vv = *(const s16x8*)(vT + vT_base + (size_t)row * 2048 +
                                   kt * 64 + (cb >> 1));
        *(s16x8*)(Vl + row * 128 + (cb ^ ((row & 7) << 4))) = vv;
      }
    }
    __syncthreads();
    // ---- S = Q K^T: this wave's 16 key-cols [wn*16, wn*16+16) ----
    f32x4 sacc[2];
    sacc[0] = (f32x4){0.f, 0.f, 0.f, 0.f};
    sacc[1] = (f32x4){0.f, 0.f, 0.f, 0.f};
    {
      int krow = wn * 16 + lr;
      int swzk = (krow & 7) << 4;
#pragma unroll
      for (int ks = 0; ks < 8; ks++) {
        s16x8 bfr = *(const s16x8*)(Kl + krow * 512 + ((ks * 64 + lg * 16) ^ swzk));
        sacc[0] = __builtin_amdgcn_mfma_f32_16x16x32_bf16(qf[0][ks], bfr, sacc[0], 0, 0, 0);
        sacc[1] = __builtin_amdgcn_mfma_f32_16x16x32_bf16(qf[1][ks], bfr, sacc[1], 0, 0, 0);
      }
    }
    __syncthreads();  // all waves done reading Kl before Sl (alias) is written
    // ---- epilogue: bias, mask, exp, weights store, S->LDS(bf16), rowsum ----
    {
      int kcol = kt * 64 + wn * 16 + lr;
      int km = kmask[b * 2048 + kcol];
#pragma unroll
      for (int fm = 0; fm < 2; fm++)
#pragma unroll
        for (int i = 0; i < 4; i++) {
          int qrow = q0 + wm * 32 + fm * 16 + lg * 4 + i;
          float lgt = sacc[fm][i] * 0.0625f +
                      bias[((size_t)b * 1024 + qrow) * 2048 + kcol];
          float s;
          if (!((qmbits >> (fm * 4 + i)) & 1u))
            s = 1.0f;               // fully-masked query row -> uniform softmax
          else
            s = km ? __expf(lgt) : 0.0f;
          rs[fm][i] += s;
          weights[((size_t)b * 1024 + qrow) * 2048 + kcol] = s;
          int srow = wm * 32 + fm * 16 + lg * 4 + i;
          int scol2 = (wn * 16 + lr) * 2;
          int sbyte = srow * 128 + ((scol2 & ~15) ^ ((srow & 7) << 4)) + (scol2 & 15);
          *(unsigned short*)(Sl + sbyte) = f2bf(s);
        }
    }
    __syncthreads();
    // ---- PV: O += S * V ----
#pragma unroll
    for (int ks = 0; ks < 2; ks++) {
      int kbyte = ks * 64 + lg * 16;
      s16x8 af[2], bfr[4];
#pragma unroll
      for (int fm = 0; fm < 2; fm++) {
        int row = wm * 32 + fm * 16 + lr;
        af[fm] = *(const s16x8*)(Sl + row * 128 + (kbyte ^ ((row & 7) << 4)));
      }
#pragma unroll
      for (int fn = 0; fn < 4; fn++) {
        int row = wn * 64 + fn * 16 + lr;
        bfr[fn] = *(const s16x8*)(Vl + row * 128 + (kbyte ^ ((row & 7) << 4)));
      }
#pragma unroll
      for (int fm = 0; fm < 2; fm++)
#pragma unroll
        for (int fn = 0; fn < 4; fn++)
          acc_o[fm][fn] = __builtin_amdgcn_mfma_f32_16x16x32_bf16(
              af[fm], bfr[fn], acc_o[fm][fn], 0, 0, 0);
    }
  }
  __syncthreads();
  // ---- rowsum reduction: 16-lane butterfly + cross-wave LDS atomics ----
  if (tid < 64) rowsum_lds[tid] = 0.f;
  __syncthreads();
#pragma unroll
  for (int fm = 0; fm < 2; fm++)
#pragma unroll
    for (int i = 0; i < 4; i++) {
      float v = rs[fm][i];
      v += __shfl_xor(v, 1);
      v += __shfl_xor(v, 2);
      v += __shfl_xor(v, 4);
      v += __shfl_xor(v, 8);
      if (lr == 0) atomicAdd(&rowsum_lds[wm * 32 + fm * 16 + lg * 4 + i], v);
    }
  __syncthreads();
  // ---- normalized O store ----
#pragma unroll
  for (int fm = 0; fm < 2; fm++)
#pragma unroll
    for (int i = 0; i < 4; i++) {
      int srow = wm * 32 + fm * 16 + lg * 4 + i;
      float rinv = 1.0f / rowsum_lds[srow];
      int qrow = q0 + srow;
#pragma unroll
      for (int fn = 0; fn < 4; fn++) {
        int d = wn * 64 + fn * 16 + lr;
        out[((size_t)b * 1024 + qrow) * 256 + d] = acc_o[fm][fn][i] * rinv;
      }
    }
  if (tid < 64) rowsum_ws[b * 1024 + q0 + tid] = rowsum_lds[tid];
}

// ---------------------------------------------------------------------------
// Rescale: weights[b,q,:] *= 1/rowsum[b,q]  (float4 grid-stride)
// ---------------------------------------------------------------------------
__global__ __launch_bounds__(256) void rescale_kernel(
    float* __restrict__ weights, const float* __restrict__ rowsum) {
  const size_t total = (size_t)32 * 1024 * 2048 / 4;  // float4 count
  size_t stride = (size_t)gridDim.x * blockDim.x;
  for (size_t i = (size_t)blockIdx.x * blockDim.x + threadIdx.x; i < total;
       i += stride) {
    size_t row = i >> 9;  // 512 float4 per row of 2048
    float rinv = 1.0f / rowsum[row];
    f32x4 v = ((const f32x4*)weights)[i];
    v[0] *= rinv; v[1] *= rinv; v[2] *= rinv; v[3] *= rinv;
    ((f32x4*)weights)[i] = v;
  }
}

extern "C" void kernel_launch(void* const* d_in, const int* in_sizes, int n_in,
                              void* d_out, int out_size, void* d_ws,
                              size_t ws_size, hipStream_t stream) {
  const float* query = (const float*)d_in[0];
  const float* key = (const float*)d_in[1];
  const float* value = (const float*)d_in[2];
  const int* qmask = (const int*)d_in[3];
  const int* kmask = (const int*)d_in[4];
  const float* bias = (const float*)d_in[5];
  const float* Wq = (const float*)d_in[6];
  const float* bq = (const float*)d_in[7];
  const float* Wk = (const float*)d_in[8];
  const float* bk = (const float*)d_in[9];
  const float* Wv = (const float*)d_in[10];
  const float* bv = (const float*)d_in[11];

  float* out = (float*)d_out;
  float* weights = out + (size_t)32 * 1024 * 256;  // tuple output, flat concat

  char* ws = (char*)d_ws;
  unsigned short* qb = (unsigned short*)ws;                       // 16 MB
  unsigned short* kbb = (unsigned short*)(ws + 16777216);         // 32 MB
  unsigned short* vT = (unsigned short*)(ws + 50331648);          // 32 MB
  float* rowsum = (float*)(ws + 83886080);                        // 128 KB

  // Projections (bf16 outputs; V stored transposed as vT[b][d][n])
  proj_kernel<0><<<dim3(256, 2), 512, 0, stream>>>(query, Wq, bq, qb);
  proj_kernel<0><<<dim3(512, 2), 512, 0, stream>>>(key, Wk, bk, kbb);
  proj_kernel<1><<<dim3(2, 512), 512, 0, stream>>>(Wv, value, bv, vT);
  // Fused attention (unnormalized weights + rowsums + normalized out)
  attn_kernel<<<dim3(512), 512, 0, stream>>>(qb, kbb, vT, qmask, kmask, bias,
                                             out, weights, rowsum);
  // Normalize weights
  rescale_kernel<<<dim3(2048), 256, 0, stream>>>(weights, rowsum);
}